// Round 4
// baseline (446.252 us; speedup 1.0000x reference)
//
#include <hip/hip_runtime.h>
#include <cmath>

// Problem constants (from reference)
#define NB 4
#define NP 8192            // 2^13 points per batch
#define NE 262144          // 2^18 edges per batch
#define NCIN 32
#define NCOUT 32
#define NH 16
#define GAMMA 4.0f
#define NFEAT (NB * NP * NCIN)      // 1,048,576 floats (4 MB)
#define TILES_PER_BATCH (NE / 64)   // for the f32 fallback

typedef _Float16 half8 __attribute__((ext_vector_type(8)));
typedef float floatx4 __attribute__((ext_vector_type(4)));

// ---------------------------------------------------------------------------
// Pre-pass: features f32 -> f16 table (streaming, ~2 us). Halves gather bytes
// (one 64 B line per edge instead of 128 B) and halves the per-XCD L2 hot
// footprint (1 MB -> 512 KB per batch table).
// ---------------------------------------------------------------------------
__global__ __launch_bounds__(256)
void cvt_f16_kernel(const float* __restrict__ features, _Float16* __restrict__ f16t)
{
    const int i = blockIdx.x * blockDim.x + threadIdx.x;    // 0 .. 131071
    const floatx4* src = (const floatx4*)features + (long)i * 2;
    floatx4 v0 = src[0], v1 = src[1];
    half8 h;
    h[0] = (_Float16)v0[0]; h[1] = (_Float16)v0[1];
    h[2] = (_Float16)v0[2]; h[3] = (_Float16)v0[3];
    h[4] = (_Float16)v1[0]; h[5] = (_Float16)v1[1];
    h[6] = (_Float16)v1[2]; h[7] = (_Float16)v1[3];
    *((half8*)f16t + i) = h;
}

// ---------------------------------------------------------------------------
// Main kernel: XCD-sharded by batch (round-3 structure), f16 gathers,
// 512-thread blocks for 32 waves/CU (exact device fill: 1024x512 threads,
// 4 blocks/CU x 33 KB LDS, 64 VGPR x 2048 thr = full register file).
//
// GEMM view: msg[e, o] = sum_k Z[e,k] * W2T[k,o],  k = h*32 + i, K = 512
//   Z[e, h*32+i] = rbf_h(e) * x_src[e][i]
// MFMA f32_16x16x32_f16 layouts (HW-verified, learn_hip m89/m91):
//   A: lane holds A[m=lane&15][k_local=(lane>>4)*8+j], j=0..7
//   B: lane holds B[k_local][n=lane&15]
//   D: lane holds D[row=(lane>>4)*4+rr][col=m]
// ---------------------------------------------------------------------------
__global__ __launch_bounds__(512, 8)
void pconv_f16_kernel(const _Float16* __restrict__ feat16,
                      const float* __restrict__ edge_vec,
                      const float* __restrict__ W,
                      const float* __restrict__ mu,
                      const int* __restrict__ edge_src,
                      const int* __restrict__ edge_dst,
                      const int* __restrict__ n_norm_p,
                      float* __restrict__ out)
{
    // W swizzled to exact B-fragment order (conflict-free b128 reads):
    //   wsw[ ((s*2+u)*64 + lane)*8 + j ] = W[h=s][o=(lane&15)+16u][i=(lane>>4)*8+j]
    __shared__ _Float16 wsw[16 * 2 * 64 * 8];   // 32 KiB
    __shared__ float mus[16];

    const int tid = threadIdx.x;
    for (int idx = tid; idx < 16384; idx += 512) {
        int j = idx & 7;
        int l = (idx >> 3) & 63;
        int u = (idx >> 9) & 1;
        int s = idx >> 10;
        int n = (l & 15) + (u << 4);          // output channel o
        int i = ((l >> 4) << 3) | j;          // input channel
        wsw[idx] = (_Float16)W[(s * NCOUT + n) * NCIN + i];
    }
    if (tid < 16) mus[tid] = mu[tid];
    __syncthreads();

    const int lane = tid & 63;
    const int wv   = tid >> 6;    // 0..7
    const int m    = lane & 15;   // A-row (edge) in main loop; D-col (channel) in epilogue
    const int q    = lane >> 4;

    const int nn = n_norm_p[0];
    const float scale = (nn > 0) ? rsqrtf((float)nn) : 1.0f;

    // XCD-shard: group g = bid&7 -> batch g>>1; the two groups per batch take
    // contiguous halves of its 16384 16-edge chunks.
    const int g   = blockIdx.x & 7;
    const int bb  = g >> 1;
    const int sub = g & 1;
    const int bi  = blockIdx.x >> 3;          // 0..127 within group
    const int w   = bi * 8 + wv;              // 0..1023: wave id within group

    const _Float16* fbase = feat16 + (((long)bb << 13) * NCIN);
    float* obase = out + (((long)bb << 13) * NCOUT);
    const long ebatch = (long)bb * NE;
    const int cbase = sub * 8192;

    #pragma unroll 1
    for (int it = 0; it < 8; ++it) {
        const int  c  = cbase + w + it * 1024;      // chunk (16 edges) in batch
        const long e0 = ebatch + (long)c * 16;
        const long ge = e0 + m;
        const int  src = edge_src[ge];

        // one 64 B line per edge; this lane's 16 B slice
        half8 xh = *(const half8*)(fbase + (long)src * NCIN + q * 8);

        const float* ev = edge_vec + ge * 3;
        float vx = ev[0], vy = ev[1], vz = ev[2];
        // self-interaction zeroing in ref is a no-op numerically (r<1e-10 -> r=0)
        float r = sqrtf(vx * vx + vy * vy + vz * vz);

        float rbf[16];
        #pragma unroll
        for (int s = 0; s < 16; ++s) {
            float d = r - mus[s];
            rbf[s] = __expf(-GAMMA * d * d);
        }

        floatx4 accLo = {0.f, 0.f, 0.f, 0.f};   // channels 0..15
        floatx4 accHi = {0.f, 0.f, 0.f, 0.f};   // channels 16..31

        #pragma unroll
        for (int s = 0; s < 16; ++s) {
            const _Float16 rh = (_Float16)rbf[s];
            half8 a = xh * rh;                   // 4x v_pk_mul_f16
            half8 b0 = *(const half8*)(wsw + ((s * 2 + 0) * 64 + lane) * 8);
            half8 b1 = *(const half8*)(wsw + ((s * 2 + 1) * 64 + lane) * 8);
            accLo = __builtin_amdgcn_mfma_f32_16x16x32_f16(a, b0, accLo, 0, 0, 0);
            accHi = __builtin_amdgcn_mfma_f32_16x16x32_f16(a, b1, accHi, 0, 0, 0);
        }

        // Epilogue: lane holds D[row = q*4+rr][col = m]; row = edge in chunk.
        // 16 lanes (same q,rr) cover 16 consecutive channels -> coalesced atomics.
        #pragma unroll
        for (int rr = 0; rr < 4; ++rr) {
            const long e2  = e0 + q * 4 + rr;
            const int  dst = edge_dst[e2];
            float* orow = obase + (long)dst * NCOUT;
            atomicAdd(orow + m,      accLo[rr] * scale);
            atomicAdd(orow + m + 16, accHi[rr] * scale);
        }
    }
}

// ---------------------------------------------------------------------------
// Fallback (no workspace): round-3 kernel, f32 gathers, 256-thr blocks.
// ---------------------------------------------------------------------------
__global__ __launch_bounds__(256, 4)
void pconv_mfma_kernel(const float* __restrict__ features,
                       const float* __restrict__ edge_vec,
                       const float* __restrict__ W,
                       const float* __restrict__ mu,
                       const int* __restrict__ edge_src,
                       const int* __restrict__ edge_dst,
                       const int* __restrict__ n_norm_p,
                       float* __restrict__ out)
{
    __shared__ _Float16 wsw[16 * 2 * 64 * 8];
    __shared__ float mus[16];

    const int tid = threadIdx.x;
    for (int idx = tid; idx < 16384; idx += 256) {
        int j = idx & 7;
        int l = (idx >> 3) & 63;
        int u = (idx >> 9) & 1;
        int s = idx >> 10;
        int n = (l & 15) + (u << 4);
        int i = ((l >> 4) << 3) | j;
        wsw[idx] = (_Float16)W[(s * NCOUT + n) * NCIN + i];
    }
    if (tid < 16) mus[tid] = mu[tid];
    __syncthreads();

    const int lane = tid & 63;
    const int wv   = tid >> 6;
    const int m    = lane & 15;
    const int q    = lane >> 4;

    const int nn = n_norm_p[0];
    const float scale = (nn > 0) ? rsqrtf((float)nn) : 1.0f;

    const int g    = blockIdx.x & 7;
    const int bb   = g >> 1;
    const int sub  = g & 1;
    const int bi   = blockIdx.x >> 3;

    const float* fbase = features + ((long)bb << 13) * NCIN;
    float* obase = out + ((long)bb << 13) * NCOUT;
    const long ebatch = (long)bb * NE;

    for (int i = bi; i < TILES_PER_BATCH / 2; i += 128) {
        const int  tloc  = (i << 1) + sub;
        const long ebase = ebatch + (long)tloc * 64 + (long)wv * 16;
        const long ge    = ebase + m;
        const int  src   = edge_src[ge];

        const float* xrow = fbase + (long)src * NCIN + q * 8;
        floatx4 xa = *(const floatx4*)(xrow);
        floatx4 xb = *(const floatx4*)(xrow + 4);

        const float* ev = edge_vec + ge * 3;
        float vx = ev[0], vy = ev[1], vz = ev[2];
        float r = sqrtf(vx * vx + vy * vy + vz * vz);

        float rbf[16];
        #pragma unroll
        for (int s = 0; s < 16; ++s) {
            float d = r - mus[s];
            rbf[s] = __expf(-GAMMA * d * d);
        }

        floatx4 accLo = {0.f, 0.f, 0.f, 0.f};
        floatx4 accHi = {0.f, 0.f, 0.f, 0.f};

        #pragma unroll
        for (int s = 0; s < 16; ++s) {
            const float rb = rbf[s];
            half8 a;
            a[0] = (_Float16)(rb * xa[0]);
            a[1] = (_Float16)(rb * xa[1]);
            a[2] = (_Float16)(rb * xa[2]);
            a[3] = (_Float16)(rb * xa[3]);
            a[4] = (_Float16)(rb * xb[0]);
            a[5] = (_Float16)(rb * xb[1]);
            a[6] = (_Float16)(rb * xb[2]);
            a[7] = (_Float16)(rb * xb[3]);
            half8 b0 = *(const half8*)(wsw + ((s * 2 + 0) * 64 + lane) * 8);
            half8 b1 = *(const half8*)(wsw + ((s * 2 + 1) * 64 + lane) * 8);
            accLo = __builtin_amdgcn_mfma_f32_16x16x32_f16(a, b0, accLo, 0, 0, 0);
            accHi = __builtin_amdgcn_mfma_f32_16x16x32_f16(a, b1, accHi, 0, 0, 0);
        }

        #pragma unroll
        for (int rr = 0; rr < 4; ++rr) {
            const long e2  = ebase + q * 4 + rr;
            const int  dst = edge_dst[e2];
            float* orow = obase + (long)dst * NCOUT;
            atomicAdd(orow + m,      accLo[rr] * scale);
            atomicAdd(orow + m + 16, accHi[rr] * scale);
        }
    }
}

extern "C" void kernel_launch(void* const* d_in, const int* in_sizes, int n_in,
                              void* d_out, int out_size, void* d_ws, size_t ws_size,
                              hipStream_t stream) {
    const float* features = (const float*)d_in[0];
    const float* edge_vec = (const float*)d_in[1];
    const float* W        = (const float*)d_in[2];
    const float* mu       = (const float*)d_in[3];
    const int*   edge_src = (const int*)d_in[4];
    const int*   edge_dst = (const int*)d_in[5];
    const int*   n_norm   = (const int*)d_in[6];
    float* out = (float*)d_out;

    // harness poisons d_out with 0xAA before every launch; we accumulate via atomics
    hipMemsetAsync(out, 0, (size_t)out_size * sizeof(float), stream);

    const size_t need = (size_t)NFEAT * sizeof(_Float16);   // 2 MB f16 table

    if (d_ws != nullptr && ws_size >= need) {
        _Float16* f16t = (_Float16*)d_ws;
        cvt_f16_kernel<<<NFEAT / 8 / 256, 256, 0, stream>>>(features, f16t);
        // grid MUST be 1024 (8 XCD groups x 128): exact device fill at 512 thr.
        pconv_f16_kernel<<<1024, 512, 0, stream>>>(f16t, edge_vec, W, mu,
                                                   edge_src, edge_dst, n_norm, out);
    } else {
        pconv_mfma_kernel<<<1024, 256, 0, stream>>>(features, edge_vec, W, mu,
                                                    edge_src, edge_dst, n_norm, out);
    }
}

// Round 5
// 248.424 us; speedup vs baseline: 1.7963x; 1.7963x over previous
//
#include <hip/hip_runtime.h>
#include <cmath>

// Problem constants (from reference)
#define NB 4
#define NP 8192            // 2^13 points per batch
#define NE 262144          // 2^18 edges per batch
#define NCIN 32
#define NCOUT 32
#define NH 16
#define GAMMA 4.0f
#define NFEAT (NB * NP * NCIN)      // 1,048,576 floats (4 MB)
#define TILES_PER_BATCH (NE / 64)

typedef _Float16 half8 __attribute__((ext_vector_type(8)));
typedef float floatx4 __attribute__((ext_vector_type(4)));

// ---------------------------------------------------------------------------
// Pre-pass: features f32 -> f16 table (streaming, ~3 us). Halves gather miss
// bytes and halves the per-XCD hot footprint (1 MB -> 512 KB per batch).
// Numerically validated: round-4 bench passed with identical absmax.
// ---------------------------------------------------------------------------
__global__ __launch_bounds__(256)
void cvt_f16_kernel(const float* __restrict__ features, _Float16* __restrict__ f16t)
{
    const int i = blockIdx.x * blockDim.x + threadIdx.x;    // 0 .. 131071
    const floatx4* src = (const floatx4*)features + (long)i * 2;
    floatx4 v0 = src[0], v1 = src[1];
    half8 h;
    h[0] = (_Float16)v0[0]; h[1] = (_Float16)v0[1];
    h[2] = (_Float16)v0[2]; h[3] = (_Float16)v0[3];
    h[4] = (_Float16)v1[0]; h[5] = (_Float16)v1[1];
    h[6] = (_Float16)v1[2]; h[7] = (_Float16)v1[3];
    *((half8*)f16t + i) = h;
}

// ---------------------------------------------------------------------------
// Main kernel: round-3 structure (best measured: 203 us main dispatch).
//   - XCD-sharded by batch: group g = bid&7 owns batch g>>1 (blocks go
//     round-robin to XCDs, learn_hip m09) -> each XCD's L2 holds ONE batch's
//     feature table.
//   - f16 gathers (512 KB hot table per XCD).
//   - NON-TEMPORAL loads for edge streams so they don't allocate in L2 and
//     evict the feature table between reuses (each src row is reused ~32x;
//     round-3 FETCH showed rows being re-fetched ~2.4x).
//   - 256-thread blocks, __launch_bounds__(256,4): VGPR=64, NO spills
//     (round 4 proved (512,8) causes scratch traffic: WRITE 190->364 MB).
//
// GEMM view: msg[e, o] = sum_k Z[e,k] * W2T[k,o],  k = h*32 + i, K = 512
//   Z[e, h*32+i] = rbf_h(e) * x_src[e][i]
// MFMA f32_16x16x32_f16 layouts (HW-verified, learn_hip m89/m91):
//   A: lane holds A[m=lane&15][k_local=(lane>>4)*8+j], j=0..7
//   B: lane holds B[k_local][n=lane&15]
//   D: lane holds D[row=(lane>>4)*4+rr][col=m]
// ---------------------------------------------------------------------------
__global__ __launch_bounds__(256, 4)
void pconv_f16_kernel(const _Float16* __restrict__ feat16,
                      const float* __restrict__ edge_vec,
                      const float* __restrict__ W,
                      const float* __restrict__ mu,
                      const int* __restrict__ edge_src,
                      const int* __restrict__ edge_dst,
                      const int* __restrict__ n_norm_p,
                      float* __restrict__ out)
{
    // W swizzled to exact B-fragment order (conflict-free b128 reads):
    //   wsw[ ((s*2+u)*64 + lane)*8 + j ] = W[h=s][o=(lane&15)+16u][i=(lane>>4)*8+j]
    __shared__ _Float16 wsw[16 * 2 * 64 * 8];   // 32 KiB
    __shared__ float mus[16];

    const int tid = threadIdx.x;
    for (int idx = tid; idx < 16384; idx += 256) {
        int j = idx & 7;
        int l = (idx >> 3) & 63;
        int u = (idx >> 9) & 1;
        int s = idx >> 10;
        int n = (l & 15) + (u << 4);          // output channel o
        int i = ((l >> 4) << 3) | j;          // input channel
        wsw[idx] = (_Float16)W[(s * NCOUT + n) * NCIN + i];
    }
    if (tid < 16) mus[tid] = mu[tid];
    __syncthreads();

    const int lane = tid & 63;
    const int wv   = tid >> 6;
    const int m    = lane & 15;   // A-row (edge) in main loop; D-col (channel) in epilogue
    const int q    = lane >> 4;

    const int nn = n_norm_p[0];
    const float scale = (nn > 0) ? rsqrtf((float)nn) : 1.0f;

    // XCD-shard: group g = bid&7 -> batch g>>1, tile parity g&1.
    const int g    = blockIdx.x & 7;
    const int bb   = g >> 1;                 // this block's batch (uniform)
    const int sub  = g & 1;
    const int bi   = blockIdx.x >> 3;        // 0..127 within group

    const _Float16* fbase = feat16 + ((long)bb << 13) * NCIN;
    float* obase = out + ((long)bb << 13) * NCOUT;
    const long ebatch = (long)bb * NE;

    for (int i = bi; i < TILES_PER_BATCH / 2; i += 128) {
        const int  tloc  = (i << 1) + sub;              // tile within batch
        const long ebase = ebatch + (long)tloc * 64 + (long)wv * 16;
        const long ge    = ebase + m;
        // stream reads: non-temporal (don't evict the feature table from L2)
        const int  src   = __builtin_nontemporal_load(edge_src + ge);

        // gather: one 64 B line per edge, L2-resident table; 16 B per lane
        half8 xh = *(const half8*)(fbase + (long)src * NCIN + q * 8);

        const float* ev = edge_vec + ge * 3;
        float vx = __builtin_nontemporal_load(ev + 0);
        float vy = __builtin_nontemporal_load(ev + 1);
        float vz = __builtin_nontemporal_load(ev + 2);
        // self-interaction zeroing in ref is a no-op numerically (r<1e-10 -> r=0)
        float r = sqrtf(vx * vx + vy * vy + vz * vz);

        float rbf[16];
        #pragma unroll
        for (int s = 0; s < 16; ++s) {
            float d = r - mus[s];
            rbf[s] = __expf(-GAMMA * d * d);
        }

        floatx4 accLo = {0.f, 0.f, 0.f, 0.f};   // channels 0..15
        floatx4 accHi = {0.f, 0.f, 0.f, 0.f};   // channels 16..31

        #pragma unroll
        for (int s = 0; s < 16; ++s) {
            const _Float16 rh = (_Float16)rbf[s];
            half8 a = xh * rh;                   // 4x v_pk_mul_f16
            half8 b0 = *(const half8*)(wsw + ((s * 2 + 0) * 64 + lane) * 8);
            half8 b1 = *(const half8*)(wsw + ((s * 2 + 1) * 64 + lane) * 8);
            accLo = __builtin_amdgcn_mfma_f32_16x16x32_f16(a, b0, accLo, 0, 0, 0);
            accHi = __builtin_amdgcn_mfma_f32_16x16x32_f16(a, b1, accHi, 0, 0, 0);
        }

        // Epilogue: lane holds D[row = q*4+rr][col = m]; row = edge within tile.
        // 16 lanes (same q,rr) cover 16 consecutive channels -> coalesced atomics.
        #pragma unroll
        for (int rr = 0; rr < 4; ++rr) {
            const long e2  = ebase + q * 4 + rr;
            const int  dst = __builtin_nontemporal_load(edge_dst + e2);
            float* orow = obase + (long)dst * NCOUT;
            atomicAdd(orow + m,      accLo[rr] * scale);
            atomicAdd(orow + m + 16, accHi[rr] * scale);
        }
    }
}

// ---------------------------------------------------------------------------
// Fallback (no workspace): round-3 kernel verbatim (f32 gathers).
// ---------------------------------------------------------------------------
__global__ __launch_bounds__(256, 4)
void pconv_mfma_kernel(const float* __restrict__ features,
                       const float* __restrict__ edge_vec,
                       const float* __restrict__ W,
                       const float* __restrict__ mu,
                       const int* __restrict__ edge_src,
                       const int* __restrict__ edge_dst,
                       const int* __restrict__ n_norm_p,
                       float* __restrict__ out)
{
    __shared__ _Float16 wsw[16 * 2 * 64 * 8];
    __shared__ float mus[16];

    const int tid = threadIdx.x;
    for (int idx = tid; idx < 16384; idx += 256) {
        int j = idx & 7;
        int l = (idx >> 3) & 63;
        int u = (idx >> 9) & 1;
        int s = idx >> 10;
        int n = (l & 15) + (u << 4);
        int i = ((l >> 4) << 3) | j;
        wsw[idx] = (_Float16)W[(s * NCOUT + n) * NCIN + i];
    }
    if (tid < 16) mus[tid] = mu[tid];
    __syncthreads();

    const int lane = tid & 63;
    const int wv   = tid >> 6;
    const int m    = lane & 15;
    const int q    = lane >> 4;

    const int nn = n_norm_p[0];
    const float scale = (nn > 0) ? rsqrtf((float)nn) : 1.0f;

    const int g    = blockIdx.x & 7;
    const int bb   = g >> 1;
    const int sub  = g & 1;
    const int bi   = blockIdx.x >> 3;

    const float* fbase = features + ((long)bb << 13) * NCIN;
    float* obase = out + ((long)bb << 13) * NCOUT;
    const long ebatch = (long)bb * NE;

    for (int i = bi; i < TILES_PER_BATCH / 2; i += 128) {
        const int  tloc  = (i << 1) + sub;
        const long ebase = ebatch + (long)tloc * 64 + (long)wv * 16;
        const long ge    = ebase + m;
        const int  src   = edge_src[ge];

        const float* xrow = fbase + (long)src * NCIN + q * 8;
        floatx4 xa = *(const floatx4*)(xrow);
        floatx4 xb = *(const floatx4*)(xrow + 4);

        const float* ev = edge_vec + ge * 3;
        float vx = ev[0], vy = ev[1], vz = ev[2];
        float r = sqrtf(vx * vx + vy * vy + vz * vz);

        float rbf[16];
        #pragma unroll
        for (int s = 0; s < 16; ++s) {
            float d = r - mus[s];
            rbf[s] = __expf(-GAMMA * d * d);
        }

        floatx4 accLo = {0.f, 0.f, 0.f, 0.f};
        floatx4 accHi = {0.f, 0.f, 0.f, 0.f};

        #pragma unroll
        for (int s = 0; s < 16; ++s) {
            const float rb = rbf[s];
            half8 a;
            a[0] = (_Float16)(rb * xa[0]);
            a[1] = (_Float16)(rb * xa[1]);
            a[2] = (_Float16)(rb * xa[2]);
            a[3] = (_Float16)(rb * xa[3]);
            a[4] = (_Float16)(rb * xb[0]);
            a[5] = (_Float16)(rb * xb[1]);
            a[6] = (_Float16)(rb * xb[2]);
            a[7] = (_Float16)(rb * xb[3]);
            half8 b0 = *(const half8*)(wsw + ((s * 2 + 0) * 64 + lane) * 8);
            half8 b1 = *(const half8*)(wsw + ((s * 2 + 1) * 64 + lane) * 8);
            accLo = __builtin_amdgcn_mfma_f32_16x16x32_f16(a, b0, accLo, 0, 0, 0);
            accHi = __builtin_amdgcn_mfma_f32_16x16x32_f16(a, b1, accHi, 0, 0, 0);
        }

        #pragma unroll
        for (int rr = 0; rr < 4; ++rr) {
            const long e2  = ebase + q * 4 + rr;
            const int  dst = edge_dst[e2];
            float* orow = obase + (long)dst * NCOUT;
            atomicAdd(orow + m,      accLo[rr] * scale);
            atomicAdd(orow + m + 16, accHi[rr] * scale);
        }
    }
}

extern "C" void kernel_launch(void* const* d_in, const int* in_sizes, int n_in,
                              void* d_out, int out_size, void* d_ws, size_t ws_size,
                              hipStream_t stream) {
    const float* features = (const float*)d_in[0];
    const float* edge_vec = (const float*)d_in[1];
    const float* W        = (const float*)d_in[2];
    const float* mu       = (const float*)d_in[3];
    const int*   edge_src = (const int*)d_in[4];
    const int*   edge_dst = (const int*)d_in[5];
    const int*   n_norm   = (const int*)d_in[6];
    float* out = (float*)d_out;

    // harness poisons d_out with 0xAA before every launch; we accumulate via atomics
    hipMemsetAsync(out, 0, (size_t)out_size * sizeof(float), stream);

    const size_t need = (size_t)NFEAT * sizeof(_Float16);   // 2 MB f16 table

    if (d_ws != nullptr && ws_size >= need) {
        _Float16* f16t = (_Float16*)d_ws;
        cvt_f16_kernel<<<NFEAT / 8 / 256, 256, 0, stream>>>(features, f16t);
        // grid MUST be 1024: 8 XCD groups x 128 blocks; 4 blocks/CU.
        pconv_f16_kernel<<<1024, 256, 0, stream>>>(f16t, edge_vec, W, mu,
                                                   edge_src, edge_dst, n_norm, out);
    } else {
        pconv_mfma_kernel<<<1024, 256, 0, stream>>>(features, edge_vec, W, mu,
                                                    edge_src, edge_dst, n_norm, out);
    }
}